// Round 5
// baseline (2118.616 us; speedup 1.0000x reference)
//
#include <hip/hip_runtime.h>

#define NN 50000
#define EE 800000
#define HH 128
#define CC 10
#define GG 128
#define NBK 782      // ceil(NN/64) buckets = GEMM tiles
#define NCH 98       // ceil(EE/8192) edge chunks
#define CHUNK 8192

typedef __attribute__((ext_vector_type(8))) short short8;
typedef __attribute__((ext_vector_type(4))) float f32x4;

// ---------- bf16 helpers (RNE) ----------
__device__ __forceinline__ ushort f2b(float f) {
    union { float f; uint u; } x; x.f = f;
    uint u = x.u;
    uint r = (u + 0x7fffu + ((u >> 16) & 1u)) >> 16;
    return (ushort)r;
}
__device__ __forceinline__ float lo2f(uint v) {
    union { uint u; float f; } x; x.u = v << 16; return x.f;
}
__device__ __forceinline__ float hi2f(uint v) {
    union { uint u; float f; } x; x.u = v & 0xffff0000u; return x.f;
}

// ---------------- bucketed edge-list build ----------------
// bucket b = dst >> 6  (64 dst nodes per bucket, matching one GEMM tile)

__global__ __launch_bounds__(256) void hist_kernel(const int* __restrict__ dst,
                                                   int* __restrict__ hist) {
    __shared__ int hc[NBK];
    const int c = blockIdx.x, t = threadIdx.x;
    for (int k = t; k < NBK; k += 256) hc[k] = 0;
    __syncthreads();
    for (int j = 0; j < 32; ++j) {
        int e = c * CHUNK + j * 256 + t;
        if (e < EE) atomicAdd(&hc[dst[e] >> 6], 1);
    }
    __syncthreads();
    for (int k = t; k < NBK; k += 256) hist[k * NCH + c] = hc[k];   // bucket-major
}

// per-bucket scan over its 98 chunk counts -> rel offsets + bucket totals
__global__ __launch_bounds__(128) void bscan_kernel(const int* __restrict__ hist,
                                                    int* __restrict__ rel,
                                                    int* __restrict__ btot) {
    __shared__ int s[128];
    const int b = blockIdx.x, t = threadIdx.x;
    int v = (t < NCH) ? hist[b * NCH + t] : 0;
    s[t] = v;
    __syncthreads();
    for (int off = 1; off < 128; off <<= 1) {
        int tt = (t >= off) ? s[t - off] : 0;
        __syncthreads();
        s[t] += tt;
        __syncthreads();
    }
    if (t < NCH) rel[b * NCH + t] = s[t] - v;   // exclusive
    if (t == 127) btot[b] = s[127];
}

// scan bucket totals -> bucketptr
__global__ __launch_bounds__(1024) void tscan_kernel(const int* __restrict__ btot,
                                                     int* __restrict__ bucketptr) {
    __shared__ int s[1024];
    const int t = threadIdx.x;
    int v = (t < NBK) ? btot[t] : 0;
    s[t] = v;
    __syncthreads();
    for (int off = 1; off < 1024; off <<= 1) {
        int tt = (t >= off) ? s[t - off] : 0;
        __syncthreads();
        s[t] += tt;
        __syncthreads();
    }
    if (t < NBK) bucketptr[t] = s[t] - v;
    if (t == 0) bucketptr[NBK] = EE;
}

// scatter edges into bucket-contiguous packed lists: (dstLocal<<16)|src
__global__ __launch_bounds__(256) void scatter_kernel(const int* __restrict__ src,
                                                      const int* __restrict__ dst,
                                                      const int* __restrict__ rel,
                                                      const int* __restrict__ bucketptr,
                                                      int* __restrict__ epk) {
    __shared__ int cur[NBK];
    const int c = blockIdx.x, t = threadIdx.x;
    for (int k = t; k < NBK; k += 256) cur[k] = bucketptr[k] + rel[k * NCH + c];
    __syncthreads();
    for (int j = 0; j < 32; ++j) {
        int e = c * CHUNK + j * 256 + t;
        if (e < EE) {
            int d = dst[e];
            int bk = d >> 6;
            int pos = atomicAdd(&cur[bk], 1);
            epk[pos] = ((d & 63) << 16) | src[e];
        }
    }
}

// ---------------- conversions ----------------

__global__ __launch_bounds__(256) void f2b_kernel(const float* __restrict__ in,
                                                  ushort* __restrict__ out, int n4) {
    int i = blockIdx.x * 256 + threadIdx.x;
    if (i < n4) {
        float4 v = ((const float4*)in)[i];
        ushort4 o;
        o.x = f2b(v.x); o.y = f2b(v.y); o.z = f2b(v.z); o.w = f2b(v.w);
        ((ushort4*)out)[i] = o;
    }
}

// transpose-convert the 6 MLP weights: wt[mi][n][k] = bf16(w_mi[k][n])
__global__ __launch_bounds__(256) void wconv_kernel(const float* w0, const float* w1,
                                                    const float* w2, const float* w3,
                                                    const float* w4, const float* w5,
                                                    ushort* __restrict__ wt) {
    const float* src;
    switch (blockIdx.y) {
        case 0: src = w0; break; case 1: src = w1; break;
        case 2: src = w2; break; case 3: src = w3; break;
        case 4: src = w4; break; default: src = w5; break;
    }
    int idx = blockIdx.x * 256 + threadIdx.x;   // 0..16383
    int n = idx >> 7, k = idx & 127;
    wt[blockIdx.y * 16384 + n * 128 + k] = f2b(src[k * 128 + n]);
}

// ---------------- fused tile: edge-parallel gather (LDS f32 atomics) + 2-GEMM MLP ----
// Block b owns nodes [64b, 64b+64). xs fp32 accumulates (1+eps)h + sum of neighbor rows.
// Then GEMM1 (fp32->bf16 at fragment read) and GEMM2 as before.

__global__ __launch_bounds__(256) void fused_tile(const ushort* __restrict__ hin,
                                                  const int* __restrict__ bucketptr,
                                                  const int* __restrict__ epk,
                                                  const ushort* __restrict__ wt1,  // [n][k]
                                                  const ushort* __restrict__ wt2,  // [n][k]
                                                  const float* __restrict__ b1,
                                                  const float* __restrict__ b2,
                                                  const float* __restrict__ epsp, int layer,
                                                  ushort* __restrict__ out) {
    __shared__ __align__(16) float xs[64][132];    // 33.8 KB fp32 accumulator
    __shared__ __align__(16) ushort hs[64][136];   // 17.4 KB hidden bf16
    const int tid = threadIdx.x;
    const int lane = tid & 63, w = tid >> 6;
    const int bkt = blockIdx.x;
    const int row0 = bkt * 64;
    const int l15 = lane & 15, lhi = lane >> 4;
    const float eps1 = 1.0f + epsp[layer];

    // ---- init xs = (1+eps)*h (each wave: one row per iter, lanes = col pairs) ----
#pragma unroll
    for (int j = 0; j < 16; ++j) {
        int r = j * 4 + w;
        int node = row0 + r;
        float2 ini = make_float2(0.f, 0.f);
        if (node < NN) {
            uint u = *(const uint*)(hin + (size_t)node * HH + lane * 2);
            ini.x = eps1 * lo2f(u);
            ini.y = eps1 * hi2f(u);
        }
        *(float2*)&xs[r][lane * 2] = ini;
    }
    __syncthreads();

    // ---- edge-parallel gather: full wave per edge, 4 edges in flight ----
    const int ebeg = bucketptr[bkt], eend = bucketptr[bkt + 1];
    for (int g = ebeg + w * 4; g < eend; g += 16) {
        int p[4];
#pragma unroll
        for (int k = 0; k < 4; ++k)
            p[k] = (g + k < eend) ? epk[g + k] : -1;
        uint v[4];
#pragma unroll
        for (int k = 0; k < 4; ++k)
            if (p[k] >= 0) {
                int sidx = p[k] & 0xffff;
                v[k] = *(const uint*)(hin + (size_t)sidx * HH + lane * 2);
            }
#pragma unroll
        for (int k = 0; k < 4; ++k)
            if (p[k] >= 0) {
                int dl = p[k] >> 16;
                atomicAdd(&xs[dl][lane * 2], lo2f(v[k]));
                atomicAdd(&xs[dl][lane * 2 + 1], hi2f(v[k]));
            }
    }

    // ---- load W1 fragments (independent of xs; overlaps atomic drain) ----
    short8 a1[2][4];
#pragma unroll
    for (int fa = 0; fa < 2; ++fa)
#pragma unroll
        for (int kt = 0; kt < 4; ++kt) {
            int n = w * 32 + fa * 16 + l15;
            int k = kt * 32 + lhi * 8;
            a1[fa][kt] = *(const short8*)(wt1 + n * HH + k);
        }
    __syncthreads();

    // ---- GEMM1 (B fragments: fp32 LDS -> bf16) ----
    f32x4 acc[2][4];
#pragma unroll
    for (int fa = 0; fa < 2; ++fa)
#pragma unroll
        for (int fb = 0; fb < 4; ++fb) acc[fa][fb] = (f32x4)(0.f);
#pragma unroll
    for (int kt = 0; kt < 4; ++kt) {
        short8 bfr[4];
#pragma unroll
        for (int fb = 0; fb < 4; ++fb) {
            const float* px = &xs[fb * 16 + l15][kt * 32 + lhi * 8];
            f32x4 lo = *(const f32x4*)px;
            f32x4 hi = *(const f32x4*)(px + 4);
            short8 t;
            t[0] = (short)f2b(lo[0]); t[1] = (short)f2b(lo[1]);
            t[2] = (short)f2b(lo[2]); t[3] = (short)f2b(lo[3]);
            t[4] = (short)f2b(hi[0]); t[5] = (short)f2b(hi[1]);
            t[6] = (short)f2b(hi[2]); t[7] = (short)f2b(hi[3]);
            bfr[fb] = t;
        }
#pragma unroll
        for (int fa = 0; fa < 2; ++fa)
#pragma unroll
            for (int fb = 0; fb < 4; ++fb)
                acc[fa][fb] = __builtin_amdgcn_mfma_f32_16x16x32_bf16(a1[fa][kt], bfr[fb],
                                                                     acc[fa][fb], 0, 0, 0);
    }

    // hidden = relu(acc + b1) -> bf16 -> hs
#pragma unroll
    for (int fa = 0; fa < 2; ++fa) {
        int nb = w * 32 + fa * 16 + lhi * 4;
        float4 bv = *(const float4*)(b1 + nb);
#pragma unroll
        for (int fb = 0; fb < 4; ++fb) {
            ushort4 o;
            o.x = f2b(fmaxf(acc[fa][fb][0] + bv.x, 0.f));
            o.y = f2b(fmaxf(acc[fa][fb][1] + bv.y, 0.f));
            o.z = f2b(fmaxf(acc[fa][fb][2] + bv.z, 0.f));
            o.w = f2b(fmaxf(acc[fa][fb][3] + bv.w, 0.f));
            *(ushort4*)&hs[fb * 16 + l15][nb] = o;
        }
    }

    // ---- load W2 fragments (straddles the barrier) ----
    short8 a2[2][4];
#pragma unroll
    for (int fa = 0; fa < 2; ++fa)
#pragma unroll
        for (int kt = 0; kt < 4; ++kt) {
            int n = w * 32 + fa * 16 + l15;
            int k = kt * 32 + lhi * 8;
            a2[fa][kt] = *(const short8*)(wt2 + n * HH + k);
        }
    __syncthreads();

    // ---- GEMM2 ----
#pragma unroll
    for (int fa = 0; fa < 2; ++fa)
#pragma unroll
        for (int fb = 0; fb < 4; ++fb) acc[fa][fb] = (f32x4)(0.f);
#pragma unroll
    for (int kt = 0; kt < 4; ++kt) {
        short8 bfr[4];
#pragma unroll
        for (int fb = 0; fb < 4; ++fb)
            bfr[fb] = *(const short8*)&hs[fb * 16 + l15][kt * 32 + lhi * 8];
#pragma unroll
        for (int fa = 0; fa < 2; ++fa)
#pragma unroll
            for (int fb = 0; fb < 4; ++fb)
                acc[fa][fb] = __builtin_amdgcn_mfma_f32_16x16x32_bf16(a2[fa][kt], bfr[fb],
                                                                     acc[fa][fb], 0, 0, 0);
    }

    // epilogue: out = relu(acc + b2) -> bf16 global
#pragma unroll
    for (int fa = 0; fa < 2; ++fa) {
        int nb = w * 32 + fa * 16 + lhi * 4;
        float4 bv = *(const float4*)(b2 + nb);
#pragma unroll
        for (int fb = 0; fb < 4; ++fb) {
            int m = row0 + fb * 16 + l15;
            if (m < NN) {
                ushort4 o;
                o.x = f2b(fmaxf(acc[fa][fb][0] + bv.x, 0.f));
                o.y = f2b(fmaxf(acc[fa][fb][1] + bv.y, 0.f));
                o.z = f2b(fmaxf(acc[fa][fb][2] + bv.z, 0.f));
                o.w = f2b(fmaxf(acc[fa][fb][3] + bv.w, 0.f));
                *(ushort4*)(out + (size_t)m * HH + nb) = o;
            }
        }
    }
}

// ---------------- sum pooling: 64 nodes/block, 256 threads, register accumulate ------

__global__ __launch_bounds__(256) void pool_kernel(const ushort* __restrict__ h,
                                                   const int* __restrict__ gid,
                                                   float* hg) {
    int j = threadIdx.x & 63;        // uint col-pair index
    int r0 = threadIdx.x >> 6;       // 0..3
    int n0 = blockIdx.x * 64;
    float ax = 0.f, ay = 0.f;
    int gcur = -1;
#pragma unroll
    for (int i = 0; i < 16; ++i) {
        int n = n0 + r0 + i * 4;
        if (n >= NN) break;
        int g = gid[n];
        if (g != gcur) {
            if (gcur >= 0) {
                atomicAdd(&hg[gcur * HH + 2 * j], ax);
                atomicAdd(&hg[gcur * HH + 2 * j + 1], ay);
            }
            gcur = g; ax = 0.f; ay = 0.f;
        }
        uint v = *(const uint*)(h + (size_t)n * HH + 2 * j);
        ax += lo2f(v); ay += hi2f(v);
    }
    if (gcur >= 0) {
        atomicAdd(&hg[gcur * HH + 2 * j], ax);
        atomicAdd(&hg[gcur * HH + 2 * j + 1], ay);
    }
}

// ---------------- classifier head (fp32) ----------------

__global__ __launch_bounds__(128) void classify_kernel(const float* __restrict__ hg,
                                                       const float* __restrict__ wc1,
                                                       const float* __restrict__ bc1,
                                                       const float* __restrict__ wc2,
                                                       const float* __restrict__ bc2,
                                                       float* __restrict__ out) {
    __shared__ float xrow[HH];
    __shared__ float trow[HH];
    int g = blockIdx.x, j = threadIdx.x;
    xrow[j] = hg[g * HH + j];
    __syncthreads();
    float s = bc1[j];
#pragma unroll 8
    for (int k = 0; k < HH; ++k) s += xrow[k] * wc1[k * HH + j];
    trow[j] = fmaxf(s, 0.f);
    __syncthreads();
    if (j < CC) {
        float o = bc2[j];
#pragma unroll 8
        for (int k = 0; k < HH; ++k) o += trow[k] * wc2[k * CC + j];
        out[g * CC + j] = o;
    }
}

extern "C" void kernel_launch(void* const* d_in, const int* in_sizes, int n_in,
                              void* d_out, int out_size, void* d_ws, size_t ws_size,
                              hipStream_t stream) {
    const float* features = (const float*)d_in[0];
    const int* src = (const int*)d_in[1];
    const int* dst = (const int*)d_in[2];
    const int* gid = (const int*)d_in[3];
    const float* eps = (const float*)d_in[4];
    const float* w1[3] = {(const float*)d_in[5], (const float*)d_in[9], (const float*)d_in[13]};
    const float* b1[3] = {(const float*)d_in[6], (const float*)d_in[10], (const float*)d_in[14]};
    const float* w2[3] = {(const float*)d_in[7], (const float*)d_in[11], (const float*)d_in[15]};
    const float* b2[3] = {(const float*)d_in[8], (const float*)d_in[12], (const float*)d_in[16]};
    const float* wc1 = (const float*)d_in[17];
    const float* bc1 = (const float*)d_in[18];
    const float* wc2 = (const float*)d_in[19];
    const float* bc2 = (const float*)d_in[20];
    float* outp = (float*)d_out;

    char* ws = (char*)d_ws;
    size_t off = 0;
    auto alloc = [&](size_t bytes) {
        void* p = ws + off;
        off += (bytes + 255) & ~(size_t)255;
        return p;
    };
    int* hist = (int*)alloc((size_t)NBK * NCH * sizeof(int));
    int* rel = (int*)alloc((size_t)NBK * NCH * sizeof(int));
    int* btot = (int*)alloc(NBK * sizeof(int));
    int* bucketptr = (int*)alloc((NBK + 1) * sizeof(int));
    int* epk = (int*)alloc(EE * sizeof(int));
    ushort* hb0 = (ushort*)alloc((size_t)NN * HH * 2);    // features bf16
    ushort* hb1 = (ushort*)alloc((size_t)NN * HH * 2);    // layer h bf16
    ushort* hb2 = (ushort*)alloc((size_t)NN * HH * 2);    // ping-pong layer h
    ushort* wtb = (ushort*)alloc(6 * 16384 * 2);          // transposed bf16 weights
    float* hg = (float*)alloc(GG * HH * sizeof(float));

    // bucketed edge-list build
    hist_kernel<<<NCH, 256, 0, stream>>>(dst, hist);
    bscan_kernel<<<NBK, 128, 0, stream>>>(hist, rel, btot);
    tscan_kernel<<<1, 1024, 0, stream>>>(btot, bucketptr);
    scatter_kernel<<<NCH, 256, 0, stream>>>(src, dst, rel, bucketptr, epk);

    // conversions
    f2b_kernel<<<(NN * HH / 4 + 255) / 256, 256, 0, stream>>>(features, hb0, NN * HH / 4);
    dim3 wg(64, 6);
    wconv_kernel<<<wg, 256, 0, stream>>>(w1[0], w2[0], w1[1], w2[1], w1[2], w2[2], wtb);
    // wtb layout: [0]=w1_0, [1]=w2_0, [2]=w1_1, [3]=w2_1, [4]=w1_2, [5]=w2_2

    // 3 GIN layers (edge-parallel gather + 2-GEMM MLP per 64-node tile)
    const ushort* hin = hb0;
    ushort* houts[3] = {hb1, hb2, hb1};
    for (int i = 0; i < 3; ++i) {
        fused_tile<<<NBK, 256, 0, stream>>>(hin, bucketptr, epk,
                                            wtb + (2 * i) * 16384, wtb + (2 * i + 1) * 16384,
                                            b1[i], b2[i], eps, i, houts[i]);
        hin = houts[i];
    }

    // pooling + classifier
    hipMemsetAsync(hg, 0, GG * HH * sizeof(float), stream);
    pool_kernel<<<(NN + 63) / 64, 256, 0, stream>>>(hb1, gid, hg);
    classify_kernel<<<GG, 128, 0, stream>>>(hg, wc1, bc1, wc2, bc2, outp);
}

// Round 6
// 246.800 us; speedup vs baseline: 8.5843x; 8.5843x over previous
//
#include <hip/hip_runtime.h>

#define NN 50000
#define EE 800000
#define HH 128
#define CC 10
#define GG 128
#define NBK 782      // ceil(NN/64) buckets = GEMM tiles
#define NCH 98       // ceil(EE/8192) edge chunks
#define CHUNK 8192

typedef __attribute__((ext_vector_type(8))) short short8;
typedef __attribute__((ext_vector_type(4))) float f32x4;

// ---------- bf16 helpers (RNE) ----------
__device__ __forceinline__ ushort f2b(float f) {
    union { float f; uint u; } x; x.f = f;
    uint u = x.u;
    uint r = (u + 0x7fffu + ((u >> 16) & 1u)) >> 16;
    return (ushort)r;
}
__device__ __forceinline__ float lo2f(uint v) {
    union { uint u; float f; } x; x.u = v << 16; return x.f;
}
__device__ __forceinline__ float hi2f(uint v) {
    union { uint u; float f; } x; x.u = v & 0xffff0000u; return x.f;
}

// ---------------- bucketed CSR build ----------------
// bucket b = dst >> 6. Packed edge word: (dstLocal<<16) | src  (src < 65536).

__global__ __launch_bounds__(256) void hist_kernel(const int* __restrict__ dst,
                                                   int* __restrict__ hist) {
    __shared__ int hc[NBK];
    const int c = blockIdx.x, t = threadIdx.x;
    for (int k = t; k < NBK; k += 256) hc[k] = 0;
    __syncthreads();
    for (int j = 0; j < 32; ++j) {
        int e = c * CHUNK + j * 256 + t;
        if (e < EE) atomicAdd(&hc[dst[e] >> 6], 1);
    }
    __syncthreads();
    for (int k = t; k < NBK; k += 256) hist[k * NCH + c] = hc[k];   // bucket-major
}

// per-bucket scan over its 98 chunk counts -> rel offsets + bucket totals
__global__ __launch_bounds__(128) void bscan_kernel(const int* __restrict__ hist,
                                                    int* __restrict__ rel,
                                                    int* __restrict__ btot) {
    __shared__ int s[128];
    const int b = blockIdx.x, t = threadIdx.x;
    int v = (t < NCH) ? hist[b * NCH + t] : 0;
    s[t] = v;
    __syncthreads();
    for (int off = 1; off < 128; off <<= 1) {
        int tt = (t >= off) ? s[t - off] : 0;
        __syncthreads();
        s[t] += tt;
        __syncthreads();
    }
    if (t < NCH) rel[b * NCH + t] = s[t] - v;   // exclusive
    if (t == 127) btot[b] = s[127];
}

// scan bucket totals -> bucketptr
__global__ __launch_bounds__(1024) void tscan_kernel(const int* __restrict__ btot,
                                                     int* __restrict__ bucketptr,
                                                     int* __restrict__ rowptr) {
    __shared__ int s[1024];
    const int t = threadIdx.x;
    int v = (t < NBK) ? btot[t] : 0;
    s[t] = v;
    __syncthreads();
    for (int off = 1; off < 1024; off <<= 1) {
        int tt = (t >= off) ? s[t - off] : 0;
        __syncthreads();
        s[t] += tt;
        __syncthreads();
    }
    if (t < NBK) bucketptr[t] = s[t] - v;
    if (t == 0) { bucketptr[NBK] = EE; rowptr[NN] = EE; }
}

// scatter edges into bucket-contiguous packed lists
__global__ __launch_bounds__(256) void scatter_kernel(const int* __restrict__ src,
                                                      const int* __restrict__ dst,
                                                      const int* __restrict__ rel,
                                                      const int* __restrict__ bucketptr,
                                                      int* __restrict__ epk) {
    __shared__ int cur[NBK];
    const int c = blockIdx.x, t = threadIdx.x;
    for (int k = t; k < NBK; k += 256) cur[k] = bucketptr[k] + rel[k * NCH + c];
    __syncthreads();
    for (int j = 0; j < 32; ++j) {
        int e = c * CHUNK + j * 256 + t;
        if (e < EE) {
            int d = dst[e];
            int bk = d >> 6;
            int pos = atomicAdd(&cur[bk], 1);
            epk[pos] = ((d & 63) << 16) | src[e];
        }
    }
}

// per-bucket counting sort -> node-ordered eidx (coalesced writes) + rowptr
__global__ __launch_bounds__(256) void bsort_kernel(const int* __restrict__ epk,
                                                    const int* __restrict__ bucketptr,
                                                    int* __restrict__ eidx,
                                                    int* __restrict__ rowptr) {
    __shared__ int cnt[64];
    __shared__ int cur[64];
    const int b = blockIdx.x, t = threadIdx.x;
    const int base = bucketptr[b], end = bucketptr[b + 1];
    if (t < 64) cnt[t] = 0;
    __syncthreads();
    for (int i = base + t; i < end; i += 256)
        atomicAdd(&cnt[(epk[i] >> 16) & 63], 1);
    __syncthreads();
    if (t < 64) {
        int v = cnt[t];
        int incl = v;
#pragma unroll
        for (int off = 1; off < 64; off <<= 1) {
            int u = __shfl_up(incl, off);
            if (t >= off) incl += u;
        }
        int excl = incl - v;
        cur[t] = excl;
        int node = b * 64 + t;
        if (node < NN) rowptr[node] = base + excl;
    }
    __syncthreads();
    for (int i = base + t; i < end; i += 256) {
        int p = epk[i];
        int dl = (p >> 16) & 63;
        int pos = atomicAdd(&cur[dl], 1);
        eidx[base + pos] = p & 0xffff;
    }
}

// ---------------- conversions ----------------

__global__ __launch_bounds__(256) void f2b_kernel(const float* __restrict__ in,
                                                  ushort* __restrict__ out, int n4) {
    int i = blockIdx.x * 256 + threadIdx.x;
    if (i < n4) {
        float4 v = ((const float4*)in)[i];
        ushort4 o;
        o.x = f2b(v.x); o.y = f2b(v.y); o.z = f2b(v.z); o.w = f2b(v.w);
        ((ushort4*)out)[i] = o;
    }
}

// transpose-convert the 6 MLP weights: wt[mi][n][k] = bf16(w_mi[k][n])
__global__ __launch_bounds__(256) void wconv_kernel(const float* w0, const float* w1,
                                                    const float* w2, const float* w3,
                                                    const float* w4, const float* w5,
                                                    ushort* __restrict__ wt) {
    const float* src;
    switch (blockIdx.y) {
        case 0: src = w0; break; case 1: src = w1; break;
        case 2: src = w2; break; case 3: src = w3; break;
        case 4: src = w4; break; default: src = w5; break;
    }
    int idx = blockIdx.x * 256 + threadIdx.x;   // 0..16383
    int n = idx >> 7, k = idx & 127;
    wt[blockIdx.y * 16384 + n * 128 + k] = f2b(src[k * 128 + n]);
}

// ---------------- aggregation: one wave per destination node (bf16, 8 in flight) ----

__global__ __launch_bounds__(256) void aggregate_kernel(const ushort* __restrict__ h,
                                                        const int* __restrict__ rowptr,
                                                        const int* __restrict__ eidx,
                                                        ushort* __restrict__ agg) {
    int node = blockIdx.x * 4 + (threadIdx.x >> 6);
    if (node >= NN) return;
    int lane = threadIdx.x & 63;
    int beg = rowptr[node], end = rowptr[node + 1];
    float ax = 0.f, ay = 0.f;
    int i = beg;
    for (; i + 8 <= end; i += 8) {
        uint v[8];
#pragma unroll
        for (int k = 0; k < 8; ++k) {
            int s = eidx[i + k];
            v[k] = *(const uint*)(h + (size_t)s * HH + lane * 2);
        }
#pragma unroll
        for (int k = 0; k < 8; ++k) { ax += lo2f(v[k]); ay += hi2f(v[k]); }
    }
    for (; i < end; ++i) {
        int s = eidx[i];
        uint v = *(const uint*)(h + (size_t)s * HH + lane * 2);
        ax += lo2f(v); ay += hi2f(v);
    }
    uint o = (uint)f2b(ax) | (((uint)f2b(ay)) << 16);
    *(uint*)(agg + (size_t)node * HH + lane * 2) = o;
}

// ---------------- fused MLP: out = relu(relu(X@W1+b1)@W2+b2), X=(1+eps)h+agg --------
// MFMA with W^T as A-operand: D[n][m] -> lane packs 4 consecutive out cols -> 8B store.

__device__ __forceinline__ uint comb2(uint hv, uint av, float e) {
    float fl = e * lo2f(hv) + lo2f(av);
    float fh = e * hi2f(hv) + hi2f(av);
    return (uint)f2b(fl) | (((uint)f2b(fh)) << 16);
}

__global__ __launch_bounds__(256) void fused_mlp(const ushort* __restrict__ xin,
                                                 const ushort* __restrict__ agg,
                                                 const ushort* __restrict__ wt1,  // [n][k]
                                                 const ushort* __restrict__ wt2,  // [n][k]
                                                 const float* __restrict__ b1,
                                                 const float* __restrict__ b2,
                                                 const float* __restrict__ epsp, int layer,
                                                 ushort* __restrict__ out, int nrows) {
    __shared__ __align__(16) ushort xs[64][136];
    __shared__ __align__(16) ushort hs[64][136];
    const int tid = threadIdx.x;
    const int lane = tid & 63, w = tid >> 6;
    const int row0 = blockIdx.x * 64;
    const int l15 = lane & 15, lhi = lane >> 4;

    short8 a1[2][4], a2[2][4];
#pragma unroll
    for (int fa = 0; fa < 2; ++fa)
#pragma unroll
        for (int kt = 0; kt < 4; ++kt) {
            int n = w * 32 + fa * 16 + l15;
            int k = kt * 32 + lhi * 8;
            a1[fa][kt] = *(const short8*)(wt1 + n * HH + k);
            a2[fa][kt] = *(const short8*)(wt2 + n * HH + k);
        }

    float eps1 = 1.0f + epsp[layer];
#pragma unroll
    for (int it = 0; it < 4; ++it) {
        int idx = it * 256 + tid;
        int r = idx >> 4, kq = idx & 15;
        int row = row0 + r;
        uint4 xv = make_uint4(0u, 0u, 0u, 0u);
        if (row < nrows) {
            xv = *(const uint4*)(xin + (size_t)row * HH + kq * 8);
            uint4 av = *(const uint4*)(agg + (size_t)row * HH + kq * 8);
            xv.x = comb2(xv.x, av.x, eps1);
            xv.y = comb2(xv.y, av.y, eps1);
            xv.z = comb2(xv.z, av.z, eps1);
            xv.w = comb2(xv.w, av.w, eps1);
        }
        *(uint4*)&xs[r][kq * 8] = xv;
    }
    __syncthreads();

    f32x4 acc[2][4];
#pragma unroll
    for (int fa = 0; fa < 2; ++fa)
#pragma unroll
        for (int fb = 0; fb < 4; ++fb) acc[fa][fb] = (f32x4)(0.f);
#pragma unroll
    for (int kt = 0; kt < 4; ++kt) {
        short8 bfr[4];
#pragma unroll
        for (int fb = 0; fb < 4; ++fb)
            bfr[fb] = *(const short8*)&xs[fb * 16 + l15][kt * 32 + lhi * 8];
#pragma unroll
        for (int fa = 0; fa < 2; ++fa)
#pragma unroll
            for (int fb = 0; fb < 4; ++fb)
                acc[fa][fb] = __builtin_amdgcn_mfma_f32_16x16x32_bf16(a1[fa][kt], bfr[fb],
                                                                     acc[fa][fb], 0, 0, 0);
    }

#pragma unroll
    for (int fa = 0; fa < 2; ++fa) {
        int nb = w * 32 + fa * 16 + lhi * 4;
        float4 bv = *(const float4*)(b1 + nb);
#pragma unroll
        for (int fb = 0; fb < 4; ++fb) {
            ushort4 o;
            o.x = f2b(fmaxf(acc[fa][fb][0] + bv.x, 0.f));
            o.y = f2b(fmaxf(acc[fa][fb][1] + bv.y, 0.f));
            o.z = f2b(fmaxf(acc[fa][fb][2] + bv.z, 0.f));
            o.w = f2b(fmaxf(acc[fa][fb][3] + bv.w, 0.f));
            *(ushort4*)&hs[fb * 16 + l15][nb] = o;
        }
    }
    __syncthreads();

#pragma unroll
    for (int fa = 0; fa < 2; ++fa)
#pragma unroll
        for (int fb = 0; fb < 4; ++fb) acc[fa][fb] = (f32x4)(0.f);
#pragma unroll
    for (int kt = 0; kt < 4; ++kt) {
        short8 bfr[4];
#pragma unroll
        for (int fb = 0; fb < 4; ++fb)
            bfr[fb] = *(const short8*)&hs[fb * 16 + l15][kt * 32 + lhi * 8];
#pragma unroll
        for (int fa = 0; fa < 2; ++fa)
#pragma unroll
            for (int fb = 0; fb < 4; ++fb)
                acc[fa][fb] = __builtin_amdgcn_mfma_f32_16x16x32_bf16(a2[fa][kt], bfr[fb],
                                                                     acc[fa][fb], 0, 0, 0);
    }

#pragma unroll
    for (int fa = 0; fa < 2; ++fa) {
        int nb = w * 32 + fa * 16 + lhi * 4;
        float4 bv = *(const float4*)(b2 + nb);
#pragma unroll
        for (int fb = 0; fb < 4; ++fb) {
            int m = row0 + fb * 16 + l15;
            if (m < nrows) {
                ushort4 o;
                o.x = f2b(fmaxf(acc[fa][fb][0] + bv.x, 0.f));
                o.y = f2b(fmaxf(acc[fa][fb][1] + bv.y, 0.f));
                o.z = f2b(fmaxf(acc[fa][fb][2] + bv.z, 0.f));
                o.w = f2b(fmaxf(acc[fa][fb][3] + bv.w, 0.f));
                *(ushort4*)(out + (size_t)m * HH + nb) = o;
            }
        }
    }
}

// ---------------- sum pooling: 64 nodes/block, 256 threads, register accumulate ------

__global__ __launch_bounds__(256) void pool_kernel(const ushort* __restrict__ h,
                                                   const int* __restrict__ gid,
                                                   float* hg) {
    int j = threadIdx.x & 63;        // uint col-pair index
    int r0 = threadIdx.x >> 6;       // 0..3
    int n0 = blockIdx.x * 64;
    float ax = 0.f, ay = 0.f;
    int gcur = -1;
#pragma unroll
    for (int i = 0; i < 16; ++i) {
        int n = n0 + r0 + i * 4;
        if (n >= NN) break;
        int g = gid[n];
        if (g != gcur) {
            if (gcur >= 0) {
                atomicAdd(&hg[gcur * HH + 2 * j], ax);
                atomicAdd(&hg[gcur * HH + 2 * j + 1], ay);
            }
            gcur = g; ax = 0.f; ay = 0.f;
        }
        uint v = *(const uint*)(h + (size_t)n * HH + 2 * j);
        ax += lo2f(v); ay += hi2f(v);
    }
    if (gcur >= 0) {
        atomicAdd(&hg[gcur * HH + 2 * j], ax);
        atomicAdd(&hg[gcur * HH + 2 * j + 1], ay);
    }
}

// ---------------- classifier head (fp32) ----------------

__global__ __launch_bounds__(128) void classify_kernel(const float* __restrict__ hg,
                                                       const float* __restrict__ wc1,
                                                       const float* __restrict__ bc1,
                                                       const float* __restrict__ wc2,
                                                       const float* __restrict__ bc2,
                                                       float* __restrict__ out) {
    __shared__ float xrow[HH];
    __shared__ float trow[HH];
    int g = blockIdx.x, j = threadIdx.x;
    xrow[j] = hg[g * HH + j];
    __syncthreads();
    float s = bc1[j];
#pragma unroll 8
    for (int k = 0; k < HH; ++k) s += xrow[k] * wc1[k * HH + j];
    trow[j] = fmaxf(s, 0.f);
    __syncthreads();
    if (j < CC) {
        float o = bc2[j];
#pragma unroll 8
        for (int k = 0; k < HH; ++k) o += trow[k] * wc2[k * CC + j];
        out[g * CC + j] = o;
    }
}

extern "C" void kernel_launch(void* const* d_in, const int* in_sizes, int n_in,
                              void* d_out, int out_size, void* d_ws, size_t ws_size,
                              hipStream_t stream) {
    const float* features = (const float*)d_in[0];
    const int* src = (const int*)d_in[1];
    const int* dst = (const int*)d_in[2];
    const int* gid = (const int*)d_in[3];
    const float* eps = (const float*)d_in[4];
    const float* w1[3] = {(const float*)d_in[5], (const float*)d_in[9], (const float*)d_in[13]};
    const float* b1[3] = {(const float*)d_in[6], (const float*)d_in[10], (const float*)d_in[14]};
    const float* w2[3] = {(const float*)d_in[7], (const float*)d_in[11], (const float*)d_in[15]};
    const float* b2[3] = {(const float*)d_in[8], (const float*)d_in[12], (const float*)d_in[16]};
    const float* wc1 = (const float*)d_in[17];
    const float* bc1 = (const float*)d_in[18];
    const float* wc2 = (const float*)d_in[19];
    const float* bc2 = (const float*)d_in[20];
    float* outp = (float*)d_out;

    char* ws = (char*)d_ws;
    size_t off = 0;
    auto alloc = [&](size_t bytes) {
        void* p = ws + off;
        off += (bytes + 255) & ~(size_t)255;
        return p;
    };
    int* hist = (int*)alloc((size_t)NBK * NCH * sizeof(int));
    int* rel = (int*)alloc((size_t)NBK * NCH * sizeof(int));
    int* btot = (int*)alloc(NBK * sizeof(int));
    int* bucketptr = (int*)alloc((NBK + 1) * sizeof(int));
    int* epk = (int*)alloc(EE * sizeof(int));
    int* eidx = (int*)alloc(EE * sizeof(int));
    int* rowptr = (int*)alloc((NN + 1) * sizeof(int));
    ushort* hb0 = (ushort*)alloc((size_t)NN * HH * 2);    // features bf16
    ushort* hb1 = (ushort*)alloc((size_t)NN * HH * 2);    // layer h bf16
    ushort* hb2 = (ushort*)alloc((size_t)NN * HH * 2);    // ping-pong layer h
    ushort* aggb = (ushort*)alloc((size_t)NN * HH * 2);   // aggregate bf16
    ushort* wtb = (ushort*)alloc(6 * 16384 * 2);          // transposed bf16 weights
    float* hg = (float*)alloc(GG * HH * sizeof(float));

    // bucketed CSR build (no 4B-scatter write amplification)
    hist_kernel<<<NCH, 256, 0, stream>>>(dst, hist);
    bscan_kernel<<<NBK, 128, 0, stream>>>(hist, rel, btot);
    tscan_kernel<<<1, 1024, 0, stream>>>(btot, bucketptr, rowptr);
    scatter_kernel<<<NCH, 256, 0, stream>>>(src, dst, rel, bucketptr, epk);
    bsort_kernel<<<NBK, 256, 0, stream>>>(epk, bucketptr, eidx, rowptr);

    // conversions
    f2b_kernel<<<(NN * HH / 4 + 255) / 256, 256, 0, stream>>>(features, hb0, NN * HH / 4);
    dim3 wg(64, 6);
    wconv_kernel<<<wg, 256, 0, stream>>>(w1[0], w2[0], w1[1], w2[1], w1[2], w2[2], wtb);
    // wtb layout: [0]=w1_0, [1]=w2_0, [2]=w1_1, [3]=w2_1, [4]=w1_2, [5]=w2_2

    const int GB = (NN + 63) / 64;  // 782

    // 3 GIN layers (aggregate at high grid/occupancy + fused 2-GEMM MLP)
    const ushort* hin = hb0;
    ushort* houts[3] = {hb1, hb2, hb1};
    for (int i = 0; i < 3; ++i) {
        aggregate_kernel<<<(NN + 3) / 4, 256, 0, stream>>>(hin, rowptr, eidx, aggb);
        fused_mlp<<<GB, 256, 0, stream>>>(hin, aggb, wtb + (2 * i) * 16384,
                                          wtb + (2 * i + 1) * 16384,
                                          b1[i], b2[i], eps, i, houts[i], NN);
        hin = houts[i];
    }

    // pooling + classifier
    hipMemsetAsync(hg, 0, GG * HH * sizeof(float), stream);
    pool_kernel<<<(NN + 63) / 64, 256, 0, stream>>>(hb1, gid, hg);
    classify_kernel<<<GG, 128, 0, stream>>>(hg, wc1, bc1, wc2, bc2, outp);
}

// Round 7
// 233.336 us; speedup vs baseline: 9.0797x; 1.0577x over previous
//
#include <hip/hip_runtime.h>

#define NN 50000
#define EE 800000
#define HH 128
#define CC 10
#define GG 128
#define NBK 782      // ceil(NN/64) buckets = GEMM tiles
#define NCH 98       // ceil(EE/8192) edge chunks
#define CHUNK 8192

typedef __attribute__((ext_vector_type(8))) short short8;
typedef __attribute__((ext_vector_type(4))) float f32x4;

// ---------- bf16 helpers (RNE) ----------
__device__ __forceinline__ ushort f2b(float f) {
    union { float f; uint u; } x; x.f = f;
    uint u = x.u;
    uint r = (u + 0x7fffu + ((u >> 16) & 1u)) >> 16;
    return (ushort)r;
}
__device__ __forceinline__ float lo2f(uint v) {
    union { uint u; float f; } x; x.u = v << 16; return x.f;
}
__device__ __forceinline__ float hi2f(uint v) {
    union { uint u; float f; } x; x.u = v & 0xffff0000u; return x.f;
}

// ---------------- bucketed CSR build ----------------
// bucket b = dst >> 6. Packed edge word: (dstLocal<<16) | src  (src < 65536).

__global__ __launch_bounds__(256) void hist_kernel(const int* __restrict__ dst,
                                                   int* __restrict__ hist) {
    __shared__ int hc[NBK];
    const int c = blockIdx.x, t = threadIdx.x;
    for (int k = t; k < NBK; k += 256) hc[k] = 0;
    __syncthreads();
    for (int j = 0; j < 32; ++j) {
        int e = c * CHUNK + j * 256 + t;
        if (e < EE) atomicAdd(&hc[dst[e] >> 6], 1);
    }
    __syncthreads();
    for (int k = t; k < NBK; k += 256) hist[k * NCH + c] = hc[k];   // bucket-major
}

// per-bucket scan over its 98 chunk counts -> rel offsets + bucket totals
__global__ __launch_bounds__(128) void bscan_kernel(const int* __restrict__ hist,
                                                    int* __restrict__ rel,
                                                    int* __restrict__ btot) {
    __shared__ int s[128];
    const int b = blockIdx.x, t = threadIdx.x;
    int v = (t < NCH) ? hist[b * NCH + t] : 0;
    s[t] = v;
    __syncthreads();
    for (int off = 1; off < 128; off <<= 1) {
        int tt = (t >= off) ? s[t - off] : 0;
        __syncthreads();
        s[t] += tt;
        __syncthreads();
    }
    if (t < NCH) rel[b * NCH + t] = s[t] - v;   // exclusive
    if (t == 127) btot[b] = s[127];
}

// scan bucket totals -> bucketptr
__global__ __launch_bounds__(1024) void tscan_kernel(const int* __restrict__ btot,
                                                     int* __restrict__ bucketptr,
                                                     int* __restrict__ rowptr) {
    __shared__ int s[1024];
    const int t = threadIdx.x;
    int v = (t < NBK) ? btot[t] : 0;
    s[t] = v;
    __syncthreads();
    for (int off = 1; off < 1024; off <<= 1) {
        int tt = (t >= off) ? s[t - off] : 0;
        __syncthreads();
        s[t] += tt;
        __syncthreads();
    }
    if (t < NBK) bucketptr[t] = s[t] - v;
    if (t == 0) { bucketptr[NBK] = EE; rowptr[NN] = EE; }
}

// scatter edges into bucket-contiguous packed lists
__global__ __launch_bounds__(256) void scatter_kernel(const int* __restrict__ src,
                                                      const int* __restrict__ dst,
                                                      const int* __restrict__ rel,
                                                      const int* __restrict__ bucketptr,
                                                      int* __restrict__ epk) {
    __shared__ int cur[NBK];
    const int c = blockIdx.x, t = threadIdx.x;
    for (int k = t; k < NBK; k += 256) cur[k] = bucketptr[k] + rel[k * NCH + c];
    __syncthreads();
    for (int j = 0; j < 32; ++j) {
        int e = c * CHUNK + j * 256 + t;
        if (e < EE) {
            int d = dst[e];
            int bk = d >> 6;
            int pos = atomicAdd(&cur[bk], 1);
            epk[pos] = ((d & 63) << 16) | src[e];
        }
    }
}

// per-bucket counting sort -> node-ordered eidx (coalesced writes) + rowptr
__global__ __launch_bounds__(256) void bsort_kernel(const int* __restrict__ epk,
                                                    const int* __restrict__ bucketptr,
                                                    int* __restrict__ eidx,
                                                    int* __restrict__ rowptr) {
    __shared__ int cnt[64];
    __shared__ int cur[64];
    const int b = blockIdx.x, t = threadIdx.x;
    const int base = bucketptr[b], end = bucketptr[b + 1];
    if (t < 64) cnt[t] = 0;
    __syncthreads();
    for (int i = base + t; i < end; i += 256)
        atomicAdd(&cnt[(epk[i] >> 16) & 63], 1);
    __syncthreads();
    if (t < 64) {
        int v = cnt[t];
        int incl = v;
#pragma unroll
        for (int off = 1; off < 64; off <<= 1) {
            int u = __shfl_up(incl, off);
            if (t >= off) incl += u;
        }
        int excl = incl - v;
        cur[t] = excl;
        int node = b * 64 + t;
        if (node < NN) rowptr[node] = base + excl;
    }
    __syncthreads();
    for (int i = base + t; i < end; i += 256) {
        int p = epk[i];
        int dl = (p >> 16) & 63;
        int pos = atomicAdd(&cur[dl], 1);
        eidx[base + pos] = p & 0xffff;
    }
}

// ---------------- conversions ----------------

__global__ __launch_bounds__(256) void f2b_kernel(const float* __restrict__ in,
                                                  ushort* __restrict__ out, int n4) {
    int i = blockIdx.x * 256 + threadIdx.x;
    if (i < n4) {
        float4 v = ((const float4*)in)[i];
        ushort4 o;
        o.x = f2b(v.x); o.y = f2b(v.y); o.z = f2b(v.z); o.w = f2b(v.w);
        ((ushort4*)out)[i] = o;
    }
}

// transpose-convert the 6 MLP weights: wt[mi][n][k] = bf16(w_mi[k][n])
__global__ __launch_bounds__(256) void wconv_kernel(const float* w0, const float* w1,
                                                    const float* w2, const float* w3,
                                                    const float* w4, const float* w5,
                                                    ushort* __restrict__ wt) {
    const float* src;
    switch (blockIdx.y) {
        case 0: src = w0; break; case 1: src = w1; break;
        case 2: src = w2; break; case 3: src = w3; break;
        case 4: src = w4; break; default: src = w5; break;
    }
    int idx = blockIdx.x * 256 + threadIdx.x;   // 0..16383
    int n = idx >> 7, k = idx & 127;
    wt[blockIdx.y * 16384 + n * 128 + k] = f2b(src[k * 128 + n]);
}

// ---------------- aggregation: one wave per dst node, half-wave uint2 gather --------
// Writes COMBINED input: xb[n] = bf16((1+eps)*h[n] + sum_{neighbors} h[s])

__global__ __launch_bounds__(256) void aggregate_kernel(const ushort* __restrict__ h,
                                                        const int* __restrict__ rowptr,
                                                        const int* __restrict__ eidx,
                                                        const float* __restrict__ epsp,
                                                        int layer,
                                                        ushort* __restrict__ xb) {
    int node = blockIdx.x * 4 + (threadIdx.x >> 6);
    if (node >= NN) return;
    int lane = threadIdx.x & 63;
    int half = lane >> 5, li = lane & 31;
    int beg = rowptr[node], end = rowptr[node + 1];
    float c0 = 0.f, c1 = 0.f, c2 = 0.f, c3 = 0.f;
    int i = beg + half;
    // main: 4 slots per half (8 edge-rows in flight per wave)
    for (; i + 6 < end; i += 8) {
        int s0 = eidx[i], s1 = eidx[i + 2], s2 = eidx[i + 4], s3 = eidx[i + 6];
        uint2 v0 = *(const uint2*)(h + (size_t)s0 * HH + li * 4);
        uint2 v1 = *(const uint2*)(h + (size_t)s1 * HH + li * 4);
        uint2 v2 = *(const uint2*)(h + (size_t)s2 * HH + li * 4);
        uint2 v3 = *(const uint2*)(h + (size_t)s3 * HH + li * 4);
        c0 += lo2f(v0.x) + lo2f(v1.x) + lo2f(v2.x) + lo2f(v3.x);
        c1 += hi2f(v0.x) + hi2f(v1.x) + hi2f(v2.x) + hi2f(v3.x);
        c2 += lo2f(v0.y) + lo2f(v1.y) + lo2f(v2.y) + lo2f(v3.y);
        c3 += hi2f(v0.y) + hi2f(v1.y) + hi2f(v2.y) + hi2f(v3.y);
    }
    for (; i < end; i += 2) {
        int s0 = eidx[i];
        uint2 v0 = *(const uint2*)(h + (size_t)s0 * HH + li * 4);
        c0 += lo2f(v0.x); c1 += hi2f(v0.x);
        c2 += lo2f(v0.y); c3 += hi2f(v0.y);
    }
    // cross-half reduce
    c0 += __shfl_xor(c0, 32);
    c1 += __shfl_xor(c1, 32);
    c2 += __shfl_xor(c2, 32);
    c3 += __shfl_xor(c3, 32);
    if (half == 0) {
        uint2 hv = *(const uint2*)(h + (size_t)node * HH + li * 4);
        float e = 1.0f + epsp[layer];
        ushort4 o;
        o.x = f2b(e * lo2f(hv.x) + c0);
        o.y = f2b(e * hi2f(hv.x) + c1);
        o.z = f2b(e * lo2f(hv.y) + c2);
        o.w = f2b(e * hi2f(hv.y) + c3);
        *(ushort4*)(xb + (size_t)node * HH + li * 4) = o;
    }
}

// ---------------- fused MLP: out = relu(relu(X@W1+b1)@W2+b2) --------------------
// X = xb (already combined). MFMA with W^T as A-operand: lane packs 4 consecutive
// out cols -> 8B stores. LAST: write h rows to xs (LDS) and pool into hg instead
// of writing h to global.

template <bool LAST>
__global__ __launch_bounds__(256) void fused_mlp(const ushort* __restrict__ xb,
                                                 const ushort* __restrict__ wt1,  // [n][k]
                                                 const ushort* __restrict__ wt2,  // [n][k]
                                                 const float* __restrict__ b1,
                                                 const float* __restrict__ b2,
                                                 const int* __restrict__ gid,
                                                 float* __restrict__ hg,
                                                 ushort* __restrict__ out, int nrows) {
    __shared__ __align__(16) ushort xs[64][136];
    __shared__ __align__(16) ushort hs[64][136];
    const int tid = threadIdx.x;
    const int lane = tid & 63, w = tid >> 6;
    const int row0 = blockIdx.x * 64;
    const int l15 = lane & 15, lhi = lane >> 4;

    short8 a1[2][4], a2[2][4];
#pragma unroll
    for (int fa = 0; fa < 2; ++fa)
#pragma unroll
        for (int kt = 0; kt < 4; ++kt) {
            int n = w * 32 + fa * 16 + l15;
            int k = kt * 32 + lhi * 8;
            a1[fa][kt] = *(const short8*)(wt1 + n * HH + k);
            a2[fa][kt] = *(const short8*)(wt2 + n * HH + k);
        }

    // stage X tile (plain copy)
#pragma unroll
    for (int it = 0; it < 4; ++it) {
        int idx = it * 256 + tid;
        int r = idx >> 4, kq = idx & 15;
        int row = row0 + r;
        uint4 xv = make_uint4(0u, 0u, 0u, 0u);
        if (row < nrows) xv = *(const uint4*)(xb + (size_t)row * HH + kq * 8);
        *(uint4*)&xs[r][kq * 8] = xv;
    }
    __syncthreads();

    f32x4 acc[2][4];
#pragma unroll
    for (int fa = 0; fa < 2; ++fa)
#pragma unroll
        for (int fb = 0; fb < 4; ++fb) acc[fa][fb] = (f32x4)(0.f);
#pragma unroll
    for (int kt = 0; kt < 4; ++kt) {
        short8 bfr[4];
#pragma unroll
        for (int fb = 0; fb < 4; ++fb)
            bfr[fb] = *(const short8*)&xs[fb * 16 + l15][kt * 32 + lhi * 8];
#pragma unroll
        for (int fa = 0; fa < 2; ++fa)
#pragma unroll
            for (int fb = 0; fb < 4; ++fb)
                acc[fa][fb] = __builtin_amdgcn_mfma_f32_16x16x32_bf16(a1[fa][kt], bfr[fb],
                                                                     acc[fa][fb], 0, 0, 0);
    }

#pragma unroll
    for (int fa = 0; fa < 2; ++fa) {
        int nb = w * 32 + fa * 16 + lhi * 4;
        float4 bv = *(const float4*)(b1 + nb);
#pragma unroll
        for (int fb = 0; fb < 4; ++fb) {
            ushort4 o;
            o.x = f2b(fmaxf(acc[fa][fb][0] + bv.x, 0.f));
            o.y = f2b(fmaxf(acc[fa][fb][1] + bv.y, 0.f));
            o.z = f2b(fmaxf(acc[fa][fb][2] + bv.z, 0.f));
            o.w = f2b(fmaxf(acc[fa][fb][3] + bv.w, 0.f));
            *(ushort4*)&hs[fb * 16 + l15][nb] = o;
        }
    }
    __syncthreads();

#pragma unroll
    for (int fa = 0; fa < 2; ++fa)
#pragma unroll
        for (int fb = 0; fb < 4; ++fb) acc[fa][fb] = (f32x4)(0.f);
#pragma unroll
    for (int kt = 0; kt < 4; ++kt) {
        short8 bfr[4];
#pragma unroll
        for (int fb = 0; fb < 4; ++fb)
            bfr[fb] = *(const short8*)&hs[fb * 16 + l15][kt * 32 + lhi * 8];
#pragma unroll
        for (int fa = 0; fa < 2; ++fa)
#pragma unroll
            for (int fb = 0; fb < 4; ++fb)
                acc[fa][fb] = __builtin_amdgcn_mfma_f32_16x16x32_bf16(a2[fa][kt], bfr[fb],
                                                                     acc[fa][fb], 0, 0, 0);
    }

#pragma unroll
    for (int fa = 0; fa < 2; ++fa) {
        int nb = w * 32 + fa * 16 + lhi * 4;
        float4 bv = *(const float4*)(b2 + nb);
#pragma unroll
        for (int fb = 0; fb < 4; ++fb) {
            int m = row0 + fb * 16 + l15;
            ushort4 o;
            o.x = f2b(fmaxf(acc[fa][fb][0] + bv.x, 0.f));
            o.y = f2b(fmaxf(acc[fa][fb][1] + bv.y, 0.f));
            o.z = f2b(fmaxf(acc[fa][fb][2] + bv.z, 0.f));
            o.w = f2b(fmaxf(acc[fa][fb][3] + bv.w, 0.f));
            if (LAST) {
                *(ushort4*)&xs[fb * 16 + l15][nb] = o;   // xs free after GEMM1
            } else if (m < nrows) {
                *(ushort4*)(out + (size_t)m * HH + nb) = o;
            }
        }
    }

    if (LAST) {
        __syncthreads();
        // pool the 64 rows in xs into hg (gid sorted -> register runs + atomic flush)
        int j = tid & 63;        // uint col-pair index
        int rg = tid >> 6;       // 0..3
        float ax = 0.f, ay = 0.f;
        int gcur = -1;
#pragma unroll
        for (int ii = 0; ii < 16; ++ii) {
            int r = rg + ii * 4;
            int n = row0 + r;
            if (n >= nrows) break;
            int g = gid[n];
            if (g != gcur) {
                if (gcur >= 0) {
                    atomicAdd(&hg[gcur * HH + 2 * j], ax);
                    atomicAdd(&hg[gcur * HH + 2 * j + 1], ay);
                }
                gcur = g; ax = 0.f; ay = 0.f;
            }
            uint v = *(const uint*)&xs[r][2 * j];
            ax += lo2f(v); ay += hi2f(v);
        }
        if (gcur >= 0) {
            atomicAdd(&hg[gcur * HH + 2 * j], ax);
            atomicAdd(&hg[gcur * HH + 2 * j + 1], ay);
        }
    }
}

// ---------------- classifier head (fp32) ----------------

__global__ __launch_bounds__(128) void classify_kernel(const float* __restrict__ hg,
                                                       const float* __restrict__ wc1,
                                                       const float* __restrict__ bc1,
                                                       const float* __restrict__ wc2,
                                                       const float* __restrict__ bc2,
                                                       float* __restrict__ out) {
    __shared__ float xrow[HH];
    __shared__ float trow[HH];
    int g = blockIdx.x, j = threadIdx.x;
    xrow[j] = hg[g * HH + j];
    __syncthreads();
    float s = bc1[j];
#pragma unroll 8
    for (int k = 0; k < HH; ++k) s += xrow[k] * wc1[k * HH + j];
    trow[j] = fmaxf(s, 0.f);
    __syncthreads();
    if (j < CC) {
        float o = bc2[j];
#pragma unroll 8
        for (int k = 0; k < HH; ++k) o += trow[k] * wc2[k * CC + j];
        out[g * CC + j] = o;
    }
}

extern "C" void kernel_launch(void* const* d_in, const int* in_sizes, int n_in,
                              void* d_out, int out_size, void* d_ws, size_t ws_size,
                              hipStream_t stream) {
    const float* features = (const float*)d_in[0];
    const int* src = (const int*)d_in[1];
    const int* dst = (const int*)d_in[2];
    const int* gid = (const int*)d_in[3];
    const float* eps = (const float*)d_in[4];
    const float* w1[3] = {(const float*)d_in[5], (const float*)d_in[9], (const float*)d_in[13]};
    const float* b1[3] = {(const float*)d_in[6], (const float*)d_in[10], (const float*)d_in[14]};
    const float* w2[3] = {(const float*)d_in[7], (const float*)d_in[11], (const float*)d_in[15]};
    const float* b2[3] = {(const float*)d_in[8], (const float*)d_in[12], (const float*)d_in[16]};
    const float* wc1 = (const float*)d_in[17];
    const float* bc1 = (const float*)d_in[18];
    const float* wc2 = (const float*)d_in[19];
    const float* bc2 = (const float*)d_in[20];
    float* outp = (float*)d_out;

    char* ws = (char*)d_ws;
    size_t off = 0;
    auto alloc = [&](size_t bytes) {
        void* p = ws + off;
        off += (bytes + 255) & ~(size_t)255;
        return p;
    };
    int* hist = (int*)alloc((size_t)NBK * NCH * sizeof(int));
    int* rel = (int*)alloc((size_t)NBK * NCH * sizeof(int));
    int* btot = (int*)alloc(NBK * sizeof(int));
    int* bucketptr = (int*)alloc((NBK + 1) * sizeof(int));
    int* epk = (int*)alloc(EE * sizeof(int));
    int* eidx = (int*)alloc(EE * sizeof(int));
    int* rowptr = (int*)alloc((NN + 1) * sizeof(int));
    ushort* hb0 = (ushort*)alloc((size_t)NN * HH * 2);    // features bf16
    ushort* hbuf = (ushort*)alloc((size_t)NN * HH * 2);   // layer h bf16
    ushort* xb = (ushort*)alloc((size_t)NN * HH * 2);     // combined MLP input bf16
    ushort* wtb = (ushort*)alloc(6 * 16384 * 2);          // transposed bf16 weights
    float* hg = (float*)alloc(GG * HH * sizeof(float));

    // bucketed CSR build (no 4B-scatter write amplification)
    hist_kernel<<<NCH, 256, 0, stream>>>(dst, hist);
    bscan_kernel<<<NBK, 128, 0, stream>>>(hist, rel, btot);
    tscan_kernel<<<1, 1024, 0, stream>>>(btot, bucketptr, rowptr);
    scatter_kernel<<<NCH, 256, 0, stream>>>(src, dst, rel, bucketptr, epk);
    bsort_kernel<<<NBK, 256, 0, stream>>>(epk, bucketptr, eidx, rowptr);

    // conversions
    f2b_kernel<<<(NN * HH / 4 + 255) / 256, 256, 0, stream>>>(features, hb0, NN * HH / 4);
    dim3 wg(64, 6);
    wconv_kernel<<<wg, 256, 0, stream>>>(w1[0], w2[0], w1[1], w2[1], w1[2], w2[2], wtb);
    // wtb layout: [0]=w1_0, [1]=w2_0, [2]=w1_1, [3]=w2_1, [4]=w1_2, [5]=w2_2

    hipMemsetAsync(hg, 0, GG * HH * sizeof(float), stream);

    const int GB = (NN + 63) / 64;  // 782
    const int AB = (NN + 3) / 4;    // 12500

    // layer 1
    aggregate_kernel<<<AB, 256, 0, stream>>>(hb0, rowptr, eidx, eps, 0, xb);
    fused_mlp<false><<<GB, 256, 0, stream>>>(xb, wtb + 0 * 16384, wtb + 1 * 16384,
                                             b1[0], b2[0], gid, hg, hbuf, NN);
    // layer 2
    aggregate_kernel<<<AB, 256, 0, stream>>>(hbuf, rowptr, eidx, eps, 1, xb);
    fused_mlp<false><<<GB, 256, 0, stream>>>(xb, wtb + 2 * 16384, wtb + 3 * 16384,
                                             b1[1], b2[1], gid, hg, hbuf, NN);
    // layer 3 (pool fused into epilogue; no h write)
    aggregate_kernel<<<AB, 256, 0, stream>>>(hbuf, rowptr, eidx, eps, 2, xb);
    fused_mlp<true><<<GB, 256, 0, stream>>>(xb, wtb + 4 * 16384, wtb + 5 * 16384,
                                            b1[2], b2[2], gid, hg, nullptr, NN);

    // classifier
    classify_kernel<<<GG, 128, 0, stream>>>(hg, wc1, bc1, wc2, bc2, outp);
}